// Round 17
// baseline (307.173 us; speedup 1.0000x reference)
//
// GraphSAGE MI355X — R17: resubmit of R16 (operand-swapped MFMA linear; R16
// hit dead container). C maps to contiguous float4/lane stores; write
// amplification 1; 16-row waves (6250 waves); no LDS.
#include <hip/hip_runtime.h>

#define D 128
#define NBK_MAX 512
#define EPB 4096        // edges per bucket-count / binscatter block
#define BSLACK 1024     // per-bucket csr slack for ×4 padding

#define SX (6.0f / 127.0f)   // int8 scale for x  (N(0,1))
#define SH (8.0f / 127.0f)   // int8 scale for h

typedef __attribute__((ext_vector_type(4))) float f32x4;
typedef __attribute__((ext_vector_type(8))) short bf16x8;
typedef unsigned short ushort_t;
typedef unsigned int uint_t;

__device__ inline ushort_t f2b(float f) {   // fp32 -> bf16 RNE
    uint_t u = __float_as_uint(f);
    u += 0x7FFF + ((u >> 16) & 1);
    return (ushort_t)(u >> 16);
}

__device__ inline uint_t q8x4(float a, float b, float c, float d, float inv_s) {
    float ra = fminf(fmaxf(rintf(a * inv_s), -127.f), 127.f);
    float rb = fminf(fmaxf(rintf(b * inv_s), -127.f), 127.f);
    float rc = fminf(fmaxf(rintf(c * inv_s), -127.f), 127.f);
    float rd = fminf(fmaxf(rintf(d * inv_s), -127.f), 127.f);
    return ((uint_t)(unsigned char)(char)(int)ra)
         | ((uint_t)(unsigned char)(char)(int)rb << 8)
         | ((uint_t)(unsigned char)(char)(int)rc << 16)
         | ((uint_t)(unsigned char)(char)(int)rd << 24);
}

// ===========================================================================
// Stage 0: per-bucket edge counts (LDS histogram; 391*391 global atomics).
// ===========================================================================
__global__ __launch_bounds__(256) void k_bucket_count(const int* __restrict__ ei,
                                                      int* __restrict__ bcnt,
                                                      int E, int nbk)
{
    __shared__ int hist[NBK_MAX];
    const int t = threadIdx.x;
    const int e0 = blockIdx.x * EPB;
    for (int i = t; i < nbk; i += 256) hist[i] = 0;
    __syncthreads();
    #pragma unroll
    for (int i = 0; i < 16; i++) {
        int e = e0 + i * 256 + t;
        if (e < E) atomicAdd(&hist[ei[E + e] >> 8], 1);
    }
    __syncthreads();
    for (int b = t; b < nbk; b += 256) {
        int c = hist[b];
        if (c) atomicAdd(&bcnt[b], c);
    }
}

__global__ __launch_bounds__(512) void k_scanb(const int* __restrict__ bcnt, int nbk,
                                               int* __restrict__ bbase,
                                               int* __restrict__ fill, int E)
{
    __shared__ int s[512];
    int t = threadIdx.x;
    int v = (t < nbk) ? bcnt[t] : 0;
    s[t] = v;
    __syncthreads();
    for (int o = 1; o < 512; o <<= 1) {
        int add = (t >= o) ? s[t - o] : 0;
        __syncthreads();
        s[t] += add;
        __syncthreads();
    }
    if (t < nbk) {
        int ex = s[t] - v;
        bbase[t] = ex;
        fill[t]  = ex;
    }
    if (t == 0) bbase[nbk] = E;
}

// ===========================================================================
// Stage 1: group edges by dst-bucket into eb (u32 {loc8<<24 | src24}).
// ===========================================================================
__global__ __launch_bounds__(256) void k_binscatter(const int* __restrict__ ei,
                                                    int* __restrict__ fill,
                                                    uint_t* __restrict__ eb,
                                                    int E, int nbk)
{
    __shared__ int hist[NBK_MAX];
    __shared__ int gbase[NBK_MAX];
    const int t = threadIdx.x;
    const int e0 = blockIdx.x * EPB;

    for (int i = t; i < nbk; i += 256) hist[i] = 0;
    __syncthreads();

    int src[16], dst[16], rank[16];
    #pragma unroll
    for (int i = 0; i < 16; i++) {
        int e = e0 + i * 256 + t;
        bool ok = (e < E);
        src[i]  = ok ? ei[e] : 0;
        dst[i]  = ok ? ei[E + e] : -1;
        rank[i] = ok ? atomicAdd(&hist[dst[i] >> 8], 1) : 0;
    }
    __syncthreads();
    for (int b = t; b < nbk; b += 256) {
        int c = hist[b];
        gbase[b] = c ? atomicAdd(&fill[b], c) : 0;
    }
    __syncthreads();
    #pragma unroll
    for (int i = 0; i < 16; i++) {
        if (dst[i] >= 0) {
            int pos = gbase[dst[i] >> 8] + rank[i];
            eb[pos] = ((uint_t)(dst[i] & 255) << 24) | (uint_t)src[i];
        }
    }
}

// ===========================================================================
// Stage 2: one block per bucket -> row_ptr (padded starts) + deg + csr_src
// (×4-padded with dummy row index).
// ===========================================================================
__global__ __launch_bounds__(256) void k_csr_fine(const uint_t* __restrict__ eb,
                                                  const int* __restrict__ bbase,
                                                  int* __restrict__ row_ptr,
                                                  int* __restrict__ deg,
                                                  int* __restrict__ csr_src,
                                                  int n, int dummy)
{
    __shared__ int s[256];
    __shared__ int pstart[256];
    __shared__ int hcnt[256];
    __shared__ int fl[256];
    const int b = blockIdx.x;
    const int t = threadIdx.x;
    const int base_eb  = bbase[b];
    const int cntb     = bbase[b + 1] - base_eb;
    const int base_csr = base_eb + BSLACK * b;

    hcnt[t] = 0; fl[t] = 0;
    __syncthreads();
    for (int i = t; i < cntb; i += 256)
        atomicAdd(&hcnt[eb[base_eb + i] >> 24], 1);
    __syncthreads();

    const int hc = hcnt[t];
    const int pc = (hc + 3) & ~3;
    s[t] = pc;
    __syncthreads();
    for (int o = 1; o < 256; o <<= 1) {
        int add = (t >= o) ? s[t - o] : 0;
        __syncthreads();
        s[t] += add;
        __syncthreads();
    }
    pstart[t] = s[t] - pc;
    int node = b * 256 + t;
    if (node < n) {
        row_ptr[node] = base_csr + pstart[t];
        deg[node] = hc;
    }
    __syncthreads();

    for (int i = t; i < cntb; i += 256) {
        uint_t e = eb[base_eb + i];
        int loc = (int)(e >> 24);
        int src = (int)(e & 0x00ffffffu);
        int off = pstart[loc] + atomicAdd(&fl[loc], 1);
        csr_src[base_csr + off] = src;
    }
    for (int k = hc; k < pc; k++)
        csr_src[base_csr + pstart[t] + k] = dummy;
}

// ===========================================================================
// cast: x -> int8 xq; zero dummy row of xq AND hq each call.
// ===========================================================================
__global__ __launch_bounds__(256) void k_cast_xq(const float* __restrict__ x,
                                                 char* __restrict__ xq,
                                                 char* __restrict__ hq,
                                                 int total8, int dummy)
{
    int i = blockIdx.x * 256 + threadIdx.x;   // one thread = 8 elems
    if (i < total8) {
        const float4* p = (const float4*)(x + (size_t)i * 8);
        float4 a = p[0], b = p[1];
        const float inv = 1.0f / SX;
        uint2 st;
        st.x = q8x4(a.x, a.y, a.z, a.w, inv);
        st.y = q8x4(b.x, b.y, b.z, b.w, inv);
        *(uint2*)(xq + (size_t)i * 8) = st;
    } else if (i < total8 + 32) {
        int k = i - total8;
        char* row = (k < 16 ? xq : hq);
        uint2 z = {0u, 0u};
        *(uint2*)(row + (size_t)dummy * D + (size_t)(k & 15) * 8) = z;
    }
}

__global__ __launch_bounds__(256) void k_prep_w(const float* __restrict__ W1l,
                                                const float* __restrict__ W1r,
                                                const float* __restrict__ W2l,
                                                const float* __restrict__ W2r,
                                                ushort_t* __restrict__ Wt1,
                                                ushort_t* __restrict__ Wt2)
{
    int idx = blockIdx.x * 256 + threadIdx.x;   // 128 cols * 256 k
    if (idx >= 128 * 256) return;
    int c = idx >> 8, k = idx & 255;
    float v1 = (k < D) ? W1l[(size_t)k * D + c] : W1r[(size_t)(k - D) * D + c];
    float v2 = (k < D) ? W2l[(size_t)k * D + c] : W2r[(size_t)(k - D) * D + c];
    Wt1[idx] = f2b(v1);
    Wt2[idx] = f2b(v2);
}

// ===========================================================================
// Aggregation: one wave per dst node, int8 gather (128 B rows), ×4-padded
// lists, int32 accumulation, bf16 mean store. (unchanged from R14)
// ===========================================================================
__global__ __launch_bounds__(256) void k_agg_i8(const char* __restrict__ featq,
                                                const int* __restrict__ row_ptr,
                                                const int* __restrict__ deg,
                                                const int* __restrict__ csr_src,
                                                ushort_t* __restrict__ meanb,
                                                float scale, int n)
{
    int gtid = blockIdx.x * 256 + threadIdx.x;
    int v    = gtid >> 6;
    if (v >= n) return;
    int lane = threadIdx.x & 63;
    int sw   = lane >> 4;
    int sl   = lane & 15;

    const int beg = row_ptr[v];
    const int dg  = deg[v];
    const int m_pad = (dg + 3) & ~3;

    const char* fq = featq + sl * 8;
    int acc[8] = {0, 0, 0, 0, 0, 0, 0, 0};

    for (int base = 0; base < m_pad; base += 64) {
        int mchunk = m_pad - base; if (mchunk > 64) mchunk = 64;
        int id = csr_src[beg + base + lane];
        int steps = mchunk >> 2;
        #pragma unroll 4
        for (int t = 0; t < steps; t++) {
            int s = __shfl(id, sw + 4 * t);
            uint2 r = *(const uint2*)(fq + (size_t)s * D);
            acc[0] += (int)(char)(r.x);
            acc[1] += (int)(char)(r.x >> 8);
            acc[2] += (int)(char)(r.x >> 16);
            acc[3] += (int)(char)(r.x >> 24);
            acc[4] += (int)(char)(r.y);
            acc[5] += (int)(char)(r.y >> 8);
            acc[6] += (int)(char)(r.y >> 16);
            acc[7] += (int)(char)(r.y >> 24);
        }
    }

    #pragma unroll
    for (int q = 0; q < 8; q++) {
        acc[q] += __shfl_xor(acc[q], 16);
        acc[q] += __shfl_xor(acc[q], 32);
    }

    if (sw == 0) {
        float f = scale / fmaxf((float)dg, 1.0f);
        uint4 st;
        st.x = (uint_t)f2b(acc[0] * f) | ((uint_t)f2b(acc[1] * f) << 16);
        st.y = (uint_t)f2b(acc[2] * f) | ((uint_t)f2b(acc[3] * f) << 16);
        st.z = (uint_t)f2b(acc[4] * f) | ((uint_t)f2b(acc[5] * f) << 16);
        st.w = (uint_t)f2b(acc[6] * f) | ((uint_t)f2b(acc[7] * f) << 16);
        *(uint4*)(meanb + (size_t)v * D + sl * 8) = st;
    }
}

// ===========================================================================
// MFMA linear (operand-swapped): wave = 16 nodes x 128 cols. B-frags = node
// features (held in regs), A-frags = Wt columns (streamed, L2-resident).
// C[i][j] = out[node j][col i]; lane l reg r -> out[node l&15]
// [col cb*16+(l>>4)*4+r] = one contiguous float4 per lane. Per-instruction
// stores: 16 rows x 64 B aligned segments -> amplification 1. No LDS.
// ===========================================================================
__global__ __launch_bounds__(256) void k_linear_mfma(const ushort_t* __restrict__ meanb,
                                                     const ushort_t* __restrict__ xinb,
                                                     const float* __restrict__ xf,
                                                     const ushort_t* __restrict__ Wt,
                                                     const float* __restrict__ bias,
                                                     float* __restrict__ outf,
                                                     ushort_t* __restrict__ outb,
                                                     char* __restrict__ outq,
                                                     int n, int npad, int relu)
{
    const int w    = threadIdx.x >> 6;
    const int lane = threadIdx.x & 63;
    const int kgrp = lane >> 4;             // 0..3
    const int l15  = lane & 15;
    const int tb   = blockIdx.x * 4 + w;    // 16-node tile index
    const int row  = tb * 16 + l15;         // this lane's node (B-frag row AND C row)
    if (tb * 16 >= npad) return;

    // B-frags: node features, k = kgrp*8 + kk*32 + e
    bf16x8 b[8];
    {
        const ushort_t* m0 = meanb + (size_t)row * D + kgrp * 8;
        #pragma unroll
        for (int kk = 0; kk < 4; kk++)
            b[kk] = *(const bf16x8*)(m0 + kk * 32);
        if (xf) {   // fp32 x source (layer 1): convert in-reg
            const float* x0 = xf + (size_t)min(row, n - 1) * D + kgrp * 8;
            #pragma unroll
            for (int kk = 0; kk < 4; kk++) {
                float4 p0 = *(const float4*)(x0 + kk * 32);
                float4 p1 = *(const float4*)(x0 + kk * 32 + 4);
                bf16x8 f;
                f[0] = (short)f2b(p0.x); f[1] = (short)f2b(p0.y);
                f[2] = (short)f2b(p0.z); f[3] = (short)f2b(p0.w);
                f[4] = (short)f2b(p1.x); f[5] = (short)f2b(p1.y);
                f[6] = (short)f2b(p1.z); f[7] = (short)f2b(p1.w);
                b[kk + 4] = f;
            }
        } else {    // bf16 source (layer 2)
            const ushort_t* x0 = xinb + (size_t)row * D + kgrp * 8;
            #pragma unroll
            for (int kk = 0; kk < 4; kk++)
                b[kk + 4] = *(const bf16x8*)(x0 + kk * 32);
        }
    }

    const bool ok = (row < n);
    const float invh = 1.0f / SH;
    #pragma unroll
    for (int cb = 0; cb < 8; cb++) {
        const int col0 = cb * 16;
        // A-frags: Wt[col0 + l15][k] (lane's A row i = l15 = output col within block)
        const ushort_t* wrow = Wt + (size_t)(col0 + l15) * 256 + kgrp * 8;
        f32x4 acc = {0.f, 0.f, 0.f, 0.f};
        #pragma unroll
        for (int kk = 0; kk < 8; kk++) {
            bf16x8 a = *(const bf16x8*)(wrow + kk * 32);
            acc = __builtin_amdgcn_mfma_f32_16x16x32_bf16(a, b[kk], acc, 0, 0, 0);
        }
        const int oc = col0 + kgrp * 4;     // lane's 4 consecutive output cols
        float4 bv = *(const float4*)(bias + oc);
        float4 v;
        v.x = acc[0] + bv.x; v.y = acc[1] + bv.y;
        v.z = acc[2] + bv.z; v.w = acc[3] + bv.w;
        if (relu) {
            v.x = fmaxf(v.x, 0.f); v.y = fmaxf(v.y, 0.f);
            v.z = fmaxf(v.z, 0.f); v.w = fmaxf(v.w, 0.f);
        }
        if (ok) {
            if (outf) *(float4*)(outf + (size_t)row * D + oc) = v;
            if (outb) {
                uint2 st;
                st.x = (uint_t)f2b(v.x) | ((uint_t)f2b(v.y) << 16);
                st.y = (uint_t)f2b(v.z) | ((uint_t)f2b(v.w) << 16);
                *(uint2*)(outb + (size_t)row * D + oc) = st;
            }
            if (outq)
                *(uint_t*)(outq + (size_t)row * D + oc) = q8x4(v.x, v.y, v.z, v.w, invh);
        }
    }
}

extern "C" void kernel_launch(void* const* d_in, const int* in_sizes, int n_in,
                              void* d_out, int out_size, void* d_ws, size_t ws_size,
                              hipStream_t stream)
{
    const float* x   = (const float*)d_in[0];
    const int*   ei  = (const int*)d_in[1];
    const float* W1l = (const float*)d_in[2];
    const float* b1  = (const float*)d_in[3];
    const float* W1r = (const float*)d_in[4];
    const float* W2l = (const float*)d_in[5];
    const float* b2  = (const float*)d_in[6];
    const float* W2r = (const float*)d_in[7];
    float* out = (float*)d_out;

    const int n = in_sizes[0] / D;   // 100000
    const int E = in_sizes[1] / 2;   // 1600000
    const int nbk = (n + 255) / 256; // 391 buckets
    const int tiles16 = (n + 15) / 16;               // 6250
    const int npad = tiles16 * 16;                   // 100000 == dummy row index

    // workspace layout (~92 MB; 102 MB proven OK in R1)
    size_t off = 0;
    auto alloc = [&](size_t bytes) { size_t o = off; off += (bytes + 511) & ~(size_t)511; return o; };
    char* ws = (char*)d_ws;
    int*      bcnt    = (int*)(ws + alloc((size_t)NBK_MAX * 4));
    int*      bbase   = (int*)(ws + alloc((size_t)(NBK_MAX + 1) * 4));
    int*      fill    = (int*)(ws + alloc((size_t)NBK_MAX * 4));
    int*      row_ptr = (int*)(ws + alloc((size_t)(n + 1) * 4));
    int*      deg     = (int*)(ws + alloc((size_t)n * 4));
    uint_t*   eb      = (uint_t*)(ws + alloc((size_t)E * 4));
    int*      csr_src = (int*)(ws + alloc(((size_t)E + (size_t)nbk * BSLACK + 64) * 4));
    ushort_t* meanb   = (ushort_t*)(ws + alloc((size_t)npad * D * 2));
    ushort_t* hb      = (ushort_t*)(ws + alloc((size_t)(npad + 1) * D * 2));
    char*     xq      = (char*)(ws + alloc((size_t)(npad + 1) * D));
    char*     hq      = (char*)(ws + alloc((size_t)(npad + 1) * D));
    ushort_t* Wt1     = (ushort_t*)(ws + alloc((size_t)128 * 256 * 2));
    ushort_t* Wt2     = (ushort_t*)(ws + alloc((size_t)128 * 256 * 2));

    hipMemsetAsync(bcnt, 0, (size_t)NBK_MAX * 4, stream);

    dim3 gB((E + EPB - 1) / EPB), gN(nbk);
    // CSR build (reused by both layers)
    k_bucket_count<<<gB, 256, 0, stream>>>(ei, bcnt, E, nbk);
    k_scanb       <<<1, 512, 0, stream>>>(bcnt, nbk, bbase, fill, E);
    k_binscatter  <<<gB, 256, 0, stream>>>(ei, fill, eb, E, nbk);
    k_csr_fine    <<<gN, 256, 0, stream>>>(eb, bbase, row_ptr, deg, csr_src, n, npad);

    // one-time casts (+ zero dummy rows of xq/hq)
    const int total8 = n * D / 8;
    k_cast_xq<<<dim3((total8 + 32 + 255) / 256), 256, 0, stream>>>(x, xq, hq, total8, npad);
    k_prep_w<<<dim3(128), 256, 0, stream>>>(W1l, W1r, W2l, W2r, Wt1, Wt2);

    dim3 gAgg((n + 3) / 4);
    dim3 gLin((tiles16 + 3) / 4);   // 4 waves/block, 1 tile/wave

    // layer 1: agg gathers int8 x; linear B-x from fp32 x; emits bf16 hb + int8 hq
    k_agg_i8     <<<gAgg, 256, 0, stream>>>(xq, row_ptr, deg, csr_src, meanb, SX, n);
    k_linear_mfma<<<gLin, 256, 0, stream>>>(meanb, (const ushort_t*)nullptr, x, Wt1, b1,
                                            (float*)nullptr, hb, hq, n, npad, 1);

    // layer 2: agg gathers int8 h; linear B-x from bf16 hb; writes fp32 out
    k_agg_i8     <<<gAgg, 256, 0, stream>>>(hq, row_ptr, deg, csr_src, meanb, SH, n);
    k_linear_mfma<<<gLin, 256, 0, stream>>>(meanb, hb, (const float*)nullptr, Wt2, b2,
                                            out, (ushort_t*)nullptr, (char*)nullptr, n, npad, 0);
}

// Round 19
// 249.945 us; speedup vs baseline: 1.2290x; 1.2290x over previous
//
// GraphSAGE MI355X — R19: resubmit of R18 (fragment-ordered Wt; R18 hit dead
// container). Coalesced A-loads: 1KB/instr contiguous, 4x fewer line requests.
#include <hip/hip_runtime.h>

#define D 128
#define NBK_MAX 512
#define EPB 4096        // edges per bucket-count / binscatter block
#define BSLACK 1024     // per-bucket csr slack for ×4 padding

#define SX (6.0f / 127.0f)   // int8 scale for x  (N(0,1))
#define SH (8.0f / 127.0f)   // int8 scale for h

typedef __attribute__((ext_vector_type(4))) float f32x4;
typedef __attribute__((ext_vector_type(8))) short bf16x8;
typedef unsigned short ushort_t;
typedef unsigned int uint_t;

__device__ inline ushort_t f2b(float f) {   // fp32 -> bf16 RNE
    uint_t u = __float_as_uint(f);
    u += 0x7FFF + ((u >> 16) & 1);
    return (ushort_t)(u >> 16);
}

__device__ inline uint_t q8x4(float a, float b, float c, float d, float inv_s) {
    float ra = fminf(fmaxf(rintf(a * inv_s), -127.f), 127.f);
    float rb = fminf(fmaxf(rintf(b * inv_s), -127.f), 127.f);
    float rc = fminf(fmaxf(rintf(c * inv_s), -127.f), 127.f);
    float rd = fminf(fmaxf(rintf(d * inv_s), -127.f), 127.f);
    return ((uint_t)(unsigned char)(char)(int)ra)
         | ((uint_t)(unsigned char)(char)(int)rb << 8)
         | ((uint_t)(unsigned char)(char)(int)rc << 16)
         | ((uint_t)(unsigned char)(char)(int)rd << 24);
}

// ===========================================================================
// Stage 0: per-bucket edge counts (LDS histogram; 391*391 global atomics).
// ===========================================================================
__global__ __launch_bounds__(256) void k_bucket_count(const int* __restrict__ ei,
                                                      int* __restrict__ bcnt,
                                                      int E, int nbk)
{
    __shared__ int hist[NBK_MAX];
    const int t = threadIdx.x;
    const int e0 = blockIdx.x * EPB;
    for (int i = t; i < nbk; i += 256) hist[i] = 0;
    __syncthreads();
    #pragma unroll
    for (int i = 0; i < 16; i++) {
        int e = e0 + i * 256 + t;
        if (e < E) atomicAdd(&hist[ei[E + e] >> 8], 1);
    }
    __syncthreads();
    for (int b = t; b < nbk; b += 256) {
        int c = hist[b];
        if (c) atomicAdd(&bcnt[b], c);
    }
}

__global__ __launch_bounds__(512) void k_scanb(const int* __restrict__ bcnt, int nbk,
                                               int* __restrict__ bbase,
                                               int* __restrict__ fill, int E)
{
    __shared__ int s[512];
    int t = threadIdx.x;
    int v = (t < nbk) ? bcnt[t] : 0;
    s[t] = v;
    __syncthreads();
    for (int o = 1; o < 512; o <<= 1) {
        int add = (t >= o) ? s[t - o] : 0;
        __syncthreads();
        s[t] += add;
        __syncthreads();
    }
    if (t < nbk) {
        int ex = s[t] - v;
        bbase[t] = ex;
        fill[t]  = ex;
    }
    if (t == 0) bbase[nbk] = E;
}

// ===========================================================================
// Stage 1: group edges by dst-bucket into eb (u32 {loc8<<24 | src24}).
// ===========================================================================
__global__ __launch_bounds__(256) void k_binscatter(const int* __restrict__ ei,
                                                    int* __restrict__ fill,
                                                    uint_t* __restrict__ eb,
                                                    int E, int nbk)
{
    __shared__ int hist[NBK_MAX];
    __shared__ int gbase[NBK_MAX];
    const int t = threadIdx.x;
    const int e0 = blockIdx.x * EPB;

    for (int i = t; i < nbk; i += 256) hist[i] = 0;
    __syncthreads();

    int src[16], dst[16], rank[16];
    #pragma unroll
    for (int i = 0; i < 16; i++) {
        int e = e0 + i * 256 + t;
        bool ok = (e < E);
        src[i]  = ok ? ei[e] : 0;
        dst[i]  = ok ? ei[E + e] : -1;
        rank[i] = ok ? atomicAdd(&hist[dst[i] >> 8], 1) : 0;
    }
    __syncthreads();
    for (int b = t; b < nbk; b += 256) {
        int c = hist[b];
        gbase[b] = c ? atomicAdd(&fill[b], c) : 0;
    }
    __syncthreads();
    #pragma unroll
    for (int i = 0; i < 16; i++) {
        if (dst[i] >= 0) {
            int pos = gbase[dst[i] >> 8] + rank[i];
            eb[pos] = ((uint_t)(dst[i] & 255) << 24) | (uint_t)src[i];
        }
    }
}

// ===========================================================================
// Stage 2: one block per bucket -> row_ptr (padded starts) + deg + csr_src
// (×4-padded with dummy row index).
// ===========================================================================
__global__ __launch_bounds__(256) void k_csr_fine(const uint_t* __restrict__ eb,
                                                  const int* __restrict__ bbase,
                                                  int* __restrict__ row_ptr,
                                                  int* __restrict__ deg,
                                                  int* __restrict__ csr_src,
                                                  int n, int dummy)
{
    __shared__ int s[256];
    __shared__ int pstart[256];
    __shared__ int hcnt[256];
    __shared__ int fl[256];
    const int b = blockIdx.x;
    const int t = threadIdx.x;
    const int base_eb  = bbase[b];
    const int cntb     = bbase[b + 1] - base_eb;
    const int base_csr = base_eb + BSLACK * b;

    hcnt[t] = 0; fl[t] = 0;
    __syncthreads();
    for (int i = t; i < cntb; i += 256)
        atomicAdd(&hcnt[eb[base_eb + i] >> 24], 1);
    __syncthreads();

    const int hc = hcnt[t];
    const int pc = (hc + 3) & ~3;
    s[t] = pc;
    __syncthreads();
    for (int o = 1; o < 256; o <<= 1) {
        int add = (t >= o) ? s[t - o] : 0;
        __syncthreads();
        s[t] += add;
        __syncthreads();
    }
    pstart[t] = s[t] - pc;
    int node = b * 256 + t;
    if (node < n) {
        row_ptr[node] = base_csr + pstart[t];
        deg[node] = hc;
    }
    __syncthreads();

    for (int i = t; i < cntb; i += 256) {
        uint_t e = eb[base_eb + i];
        int loc = (int)(e >> 24);
        int src = (int)(e & 0x00ffffffu);
        int off = pstart[loc] + atomicAdd(&fl[loc], 1);
        csr_src[base_csr + off] = src;
    }
    for (int k = hc; k < pc; k++)
        csr_src[base_csr + pstart[t] + k] = dummy;
}

// ===========================================================================
// cast: x -> int8 xq; zero dummy row of xq AND hq each call.
// ===========================================================================
__global__ __launch_bounds__(256) void k_cast_xq(const float* __restrict__ x,
                                                 char* __restrict__ xq,
                                                 char* __restrict__ hq,
                                                 int total8, int dummy)
{
    int i = blockIdx.x * 256 + threadIdx.x;   // one thread = 8 elems
    if (i < total8) {
        const float4* p = (const float4*)(x + (size_t)i * 8);
        float4 a = p[0], b = p[1];
        const float inv = 1.0f / SX;
        uint2 st;
        st.x = q8x4(a.x, a.y, a.z, a.w, inv);
        st.y = q8x4(b.x, b.y, b.z, b.w, inv);
        *(uint2*)(xq + (size_t)i * 8) = st;
    } else if (i < total8 + 32) {
        int k = i - total8;
        char* row = (k < 16 ? xq : hq);
        uint2 z = {0u, 0u};
        *(uint2*)(row + (size_t)dummy * D + (size_t)(k & 15) * 8) = z;
    }
}

// ===========================================================================
// weights -> FRAGMENT-ORDERED bf16:
// Wtf[((cb*8+kk)*64 + lane)*8 + e] = W_stacked[k][col],
//   col = cb*16 + (lane&15),  k = kk*32 + (lane>>4)*8 + e
// so the linear's A-frag load (per cb,kk) is 64 lanes x 16 B = 1 KB contiguous.
// ===========================================================================
__global__ __launch_bounds__(256) void k_prep_wf(const float* __restrict__ W1l,
                                                 const float* __restrict__ W1r,
                                                 const float* __restrict__ W2l,
                                                 const float* __restrict__ W2r,
                                                 ushort_t* __restrict__ Wtf1,
                                                 ushort_t* __restrict__ Wtf2)
{
    int j = blockIdx.x * 256 + threadIdx.x;   // 0..4095 = (cb,kk,lane)
    if (j >= 8 * 8 * 64) return;
    int lane = j & 63;
    int kk   = (j >> 6) & 7;
    int cb   = j >> 9;
    int col  = cb * 16 + (lane & 15);
    int kbase = kk * 32 + (lane >> 4) * 8;
    ushort_t o1[8], o2[8];
    #pragma unroll
    for (int e = 0; e < 8; e++) {
        int k = kbase + e;
        float v1 = (k < D) ? W1l[(size_t)k * D + col] : W1r[(size_t)(k - D) * D + col];
        float v2 = (k < D) ? W2l[(size_t)k * D + col] : W2r[(size_t)(k - D) * D + col];
        o1[e] = f2b(v1);
        o2[e] = f2b(v2);
    }
    uint4 s1, s2;
    s1.x = (uint_t)o1[0] | ((uint_t)o1[1] << 16);
    s1.y = (uint_t)o1[2] | ((uint_t)o1[3] << 16);
    s1.z = (uint_t)o1[4] | ((uint_t)o1[5] << 16);
    s1.w = (uint_t)o1[6] | ((uint_t)o1[7] << 16);
    s2.x = (uint_t)o2[0] | ((uint_t)o2[1] << 16);
    s2.y = (uint_t)o2[2] | ((uint_t)o2[3] << 16);
    s2.z = (uint_t)o2[4] | ((uint_t)o2[5] << 16);
    s2.w = (uint_t)o2[6] | ((uint_t)o2[7] << 16);
    *(uint4*)(Wtf1 + (size_t)j * 8) = s1;
    *(uint4*)(Wtf2 + (size_t)j * 8) = s2;
}

// ===========================================================================
// Aggregation: one wave per dst node, int8 gather (128 B rows), ×4-padded
// lists, int32 accumulation, bf16 mean store. (unchanged from R14)
// ===========================================================================
__global__ __launch_bounds__(256) void k_agg_i8(const char* __restrict__ featq,
                                                const int* __restrict__ row_ptr,
                                                const int* __restrict__ deg,
                                                const int* __restrict__ csr_src,
                                                ushort_t* __restrict__ meanb,
                                                float scale, int n)
{
    int gtid = blockIdx.x * 256 + threadIdx.x;
    int v    = gtid >> 6;
    if (v >= n) return;
    int lane = threadIdx.x & 63;
    int sw   = lane >> 4;
    int sl   = lane & 15;

    const int beg = row_ptr[v];
    const int dg  = deg[v];
    const int m_pad = (dg + 3) & ~3;

    const char* fq = featq + sl * 8;
    int acc[8] = {0, 0, 0, 0, 0, 0, 0, 0};

    for (int base = 0; base < m_pad; base += 64) {
        int mchunk = m_pad - base; if (mchunk > 64) mchunk = 64;
        int id = csr_src[beg + base + lane];
        int steps = mchunk >> 2;
        #pragma unroll 4
        for (int t = 0; t < steps; t++) {
            int s = __shfl(id, sw + 4 * t);
            uint2 r = *(const uint2*)(fq + (size_t)s * D);
            acc[0] += (int)(char)(r.x);
            acc[1] += (int)(char)(r.x >> 8);
            acc[2] += (int)(char)(r.x >> 16);
            acc[3] += (int)(char)(r.x >> 24);
            acc[4] += (int)(char)(r.y);
            acc[5] += (int)(char)(r.y >> 8);
            acc[6] += (int)(char)(r.y >> 16);
            acc[7] += (int)(char)(r.y >> 24);
        }
    }

    #pragma unroll
    for (int q = 0; q < 8; q++) {
        acc[q] += __shfl_xor(acc[q], 16);
        acc[q] += __shfl_xor(acc[q], 32);
    }

    if (sw == 0) {
        float f = scale / fmaxf((float)dg, 1.0f);
        uint4 st;
        st.x = (uint_t)f2b(acc[0] * f) | ((uint_t)f2b(acc[1] * f) << 16);
        st.y = (uint_t)f2b(acc[2] * f) | ((uint_t)f2b(acc[3] * f) << 16);
        st.z = (uint_t)f2b(acc[4] * f) | ((uint_t)f2b(acc[5] * f) << 16);
        st.w = (uint_t)f2b(acc[6] * f) | ((uint_t)f2b(acc[7] * f) << 16);
        *(uint4*)(meanb + (size_t)v * D + sl * 8) = st;
    }
}

// ===========================================================================
// MFMA linear (operand-swapped, frag-ordered Wt): wave = 16 nodes x 128 cols.
// B-frags = node features (regs), A-frags = Wtf streamed (1 KB contiguous
// per load instr, L2-resident). Lane l reg r -> out[node l&15]
// [col cb*16+(l>>4)*4+r] = contiguous float4 store per lane.
// ===========================================================================
__global__ __launch_bounds__(256) void k_linear_mfma(const ushort_t* __restrict__ meanb,
                                                     const ushort_t* __restrict__ xinb,
                                                     const float* __restrict__ xf,
                                                     const ushort_t* __restrict__ Wtf,
                                                     const float* __restrict__ bias,
                                                     float* __restrict__ outf,
                                                     ushort_t* __restrict__ outb,
                                                     char* __restrict__ outq,
                                                     int n, int npad, int relu)
{
    const int w    = threadIdx.x >> 6;
    const int lane = threadIdx.x & 63;
    const int kgrp = lane >> 4;             // 0..3
    const int l15  = lane & 15;
    const int tb   = blockIdx.x * 4 + w;    // 16-node tile index
    const int row  = tb * 16 + l15;         // this lane's node (B-frag row AND C row)
    if (tb * 16 >= npad) return;

    // B-frags: node features, k = kgrp*8 + kk*32 + e
    bf16x8 b[8];
    {
        const ushort_t* m0 = meanb + (size_t)row * D + kgrp * 8;
        #pragma unroll
        for (int kk = 0; kk < 4; kk++)
            b[kk] = *(const bf16x8*)(m0 + kk * 32);
        if (xf) {   // fp32 x source (layer 1): convert in-reg
            const float* x0 = xf + (size_t)min(row, n - 1) * D + kgrp * 8;
            #pragma unroll
            for (int kk = 0; kk < 4; kk++) {
                float4 p0 = *(const float4*)(x0 + kk * 32);
                float4 p1 = *(const float4*)(x0 + kk * 32 + 4);
                bf16x8 f;
                f[0] = (short)f2b(p0.x); f[1] = (short)f2b(p0.y);
                f[2] = (short)f2b(p0.z); f[3] = (short)f2b(p0.w);
                f[4] = (short)f2b(p1.x); f[5] = (short)f2b(p1.y);
                f[6] = (short)f2b(p1.z); f[7] = (short)f2b(p1.w);
                b[kk + 4] = f;
            }
        } else {    // bf16 source (layer 2)
            const ushort_t* x0 = xinb + (size_t)row * D + kgrp * 8;
            #pragma unroll
            for (int kk = 0; kk < 4; kk++)
                b[kk + 4] = *(const bf16x8*)(x0 + kk * 32);
        }
    }

    const bool ok = (row < n);
    const float invh = 1.0f / SH;
    #pragma unroll
    for (int cb = 0; cb < 8; cb++) {
        f32x4 acc = {0.f, 0.f, 0.f, 0.f};
        // A-frags: fragment-ordered, addr = (cb*512 + kk*64 + lane)*8 ushorts
        const ushort_t* wbase = Wtf + ((size_t)cb * 512 + lane) * 8;
        #pragma unroll
        for (int kk = 0; kk < 8; kk++) {
            bf16x8 a = *(const bf16x8*)(wbase + (size_t)kk * 64 * 8);
            acc = __builtin_amdgcn_mfma_f32_16x16x32_bf16(a, b[kk], acc, 0, 0, 0);
        }
        const int oc = cb * 16 + kgrp * 4;  // lane's 4 consecutive output cols
        float4 bv = *(const float4*)(bias + oc);
        float4 v;
        v.x = acc[0] + bv.x; v.y = acc[1] + bv.y;
        v.z = acc[2] + bv.z; v.w = acc[3] + bv.w;
        if (relu) {
            v.x = fmaxf(v.x, 0.f); v.y = fmaxf(v.y, 0.f);
            v.z = fmaxf(v.z, 0.f); v.w = fmaxf(v.w, 0.f);
        }
        if (ok) {
            if (outf) *(float4*)(outf + (size_t)row * D + oc) = v;
            if (outb) {
                uint2 st;
                st.x = (uint_t)f2b(v.x) | ((uint_t)f2b(v.y) << 16);
                st.y = (uint_t)f2b(v.z) | ((uint_t)f2b(v.w) << 16);
                *(uint2*)(outb + (size_t)row * D + oc) = st;
            }
            if (outq)
                *(uint_t*)(outq + (size_t)row * D + oc) = q8x4(v.x, v.y, v.z, v.w, invh);
        }
    }
}

extern "C" void kernel_launch(void* const* d_in, const int* in_sizes, int n_in,
                              void* d_out, int out_size, void* d_ws, size_t ws_size,
                              hipStream_t stream)
{
    const float* x   = (const float*)d_in[0];
    const int*   ei  = (const int*)d_in[1];
    const float* W1l = (const float*)d_in[2];
    const float* b1  = (const float*)d_in[3];
    const float* W1r = (const float*)d_in[4];
    const float* W2l = (const float*)d_in[5];
    const float* b2  = (const float*)d_in[6];
    const float* W2r = (const float*)d_in[7];
    float* out = (float*)d_out;

    const int n = in_sizes[0] / D;   // 100000
    const int E = in_sizes[1] / 2;   // 1600000
    const int nbk = (n + 255) / 256; // 391 buckets
    const int tiles16 = (n + 15) / 16;               // 6250
    const int npad = tiles16 * 16;                   // 100000 == dummy row index

    // workspace layout (~92 MB; 102 MB proven OK in R1)
    size_t off = 0;
    auto alloc = [&](size_t bytes) { size_t o = off; off += (bytes + 511) & ~(size_t)511; return o; };
    char* ws = (char*)d_ws;
    int*      bcnt    = (int*)(ws + alloc((size_t)NBK_MAX * 4));
    int*      bbase   = (int*)(ws + alloc((size_t)(NBK_MAX + 1) * 4));
    int*      fill    = (int*)(ws + alloc((size_t)NBK_MAX * 4));
    int*      row_ptr = (int*)(ws + alloc((size_t)(n + 1) * 4));
    int*      deg     = (int*)(ws + alloc((size_t)n * 4));
    uint_t*   eb      = (uint_t*)(ws + alloc((size_t)E * 4));
    int*      csr_src = (int*)(ws + alloc(((size_t)E + (size_t)nbk * BSLACK + 64) * 4));
    ushort_t* meanb   = (ushort_t*)(ws + alloc((size_t)npad * D * 2));
    ushort_t* hb      = (ushort_t*)(ws + alloc((size_t)(npad + 1) * D * 2));
    char*     xq      = (char*)(ws + alloc((size_t)(npad + 1) * D));
    char*     hq      = (char*)(ws + alloc((size_t)(npad + 1) * D));
    ushort_t* Wtf1    = (ushort_t*)(ws + alloc((size_t)128 * 256 * 2));
    ushort_t* Wtf2    = (ushort_t*)(ws + alloc((size_t)128 * 256 * 2));

    hipMemsetAsync(bcnt, 0, (size_t)NBK_MAX * 4, stream);

    dim3 gB((E + EPB - 1) / EPB), gN(nbk);
    // CSR build (reused by both layers)
    k_bucket_count<<<gB, 256, 0, stream>>>(ei, bcnt, E, nbk);
    k_scanb       <<<1, 512, 0, stream>>>(bcnt, nbk, bbase, fill, E);
    k_binscatter  <<<gB, 256, 0, stream>>>(ei, fill, eb, E, nbk);
    k_csr_fine    <<<gN, 256, 0, stream>>>(eb, bbase, row_ptr, deg, csr_src, n, npad);

    // one-time casts (+ zero dummy rows of xq/hq); fragment-ordered weights
    const int total8 = n * D / 8;
    k_cast_xq<<<dim3((total8 + 32 + 255) / 256), 256, 0, stream>>>(x, xq, hq, total8, npad);
    k_prep_wf<<<dim3(16), 256, 0, stream>>>(W1l, W1r, W2l, W2r, Wtf1, Wtf2);

    dim3 gAgg((n + 3) / 4);
    dim3 gLin((tiles16 + 3) / 4);   // 4 waves/block, 1 tile/wave

    // layer 1: agg gathers int8 x; linear B-x from fp32 x; emits bf16 hb + int8 hq
    k_agg_i8     <<<gAgg, 256, 0, stream>>>(xq, row_ptr, deg, csr_src, meanb, SX, n);
    k_linear_mfma<<<gLin, 256, 0, stream>>>(meanb, (const ushort_t*)nullptr, x, Wtf1, b1,
                                            (float*)nullptr, hb, hq, n, npad, 1);

    // layer 2: agg gathers int8 h; linear B-x from bf16 hb; writes fp32 out
    k_agg_i8     <<<gAgg, 256, 0, stream>>>(hq, row_ptr, deg, csr_src, meanb, SH, n);
    k_linear_mfma<<<gLin, 256, 0, stream>>>(meanb, hb, (const float*)nullptr, Wtf2, b2,
                                            out, (ushort_t*)nullptr, (char*)nullptr, n, npad, 0);
}